// Round 1
// baseline (1434.047 us; speedup 1.0000x reference)
//
#include <hip/hip_runtime.h>
#include <math.h>

// Gradient clipping: global L2 norm over 5 fp32 tensors, then scale all.
// Memory-bound: 2 reads + 1 write of 810 MB => ~2.43 GB HBM traffic.
//
// Structure:
//   memset(acc=0)  ->  reduce_sq (sum of squares into double via atomicAdd)
//                  ->  scale (read scalar, stream-scale all tensors into d_out)

#define NT 5
#define BLOCK 256
#define GRID 2048

struct Args5 {
    const float4* p[NT];
    long long n4[NT];   // element count in float4 units (all sizes % 4 == 0)
};

__global__ __launch_bounds__(BLOCK) void reduce_sq_kernel(Args5 args, double* acc) {
    const long long stride = (long long)gridDim.x * BLOCK;
    const long long tid = (long long)blockIdx.x * BLOCK + threadIdx.x;

    double local = 0.0;
    for (int t = 0; t < NT; ++t) {
        const float4* __restrict__ p = args.p[t];
        const long long n4 = args.n4[t];
        for (long long i = tid; i < n4; i += stride) {
            float4 v = p[i];
            float s = v.x * v.x + v.y * v.y + v.z * v.z + v.w * v.w;
            local += (double)s;
        }
    }

    // wave(64) butterfly reduce
    for (int off = 32; off > 0; off >>= 1)
        local += __shfl_down(local, off, 64);

    __shared__ double smem[BLOCK / 64];
    const int lane = threadIdx.x & 63;
    const int wave = threadIdx.x >> 6;
    if (lane == 0) smem[wave] = local;
    __syncthreads();
    if (threadIdx.x == 0) {
        double s = 0.0;
        #pragma unroll
        for (int w = 0; w < BLOCK / 64; ++w) s += smem[w];
        atomicAdd(acc, s);   // device-scope fp64 atomic (gfx950 HW)
    }
}

__global__ __launch_bounds__(BLOCK) void scale_kernel(Args5 args, float4* out, const double* acc) {
    // Uniform read -> compiler emits scalar load; L2-broadcast, negligible.
    const double nsq = *acc;
    const float norm = (float)sqrt(nsq);
    const float scale = (norm > 1.0f) ? (1.0f / (norm + 1e-6f)) : 1.0f;

    const long long stride = (long long)gridDim.x * BLOCK;
    const long long tid = (long long)blockIdx.x * BLOCK + threadIdx.x;

    long long base = 0;
    for (int t = 0; t < NT; ++t) {
        const float4* __restrict__ p = args.p[t];
        const long long n4 = args.n4[t];
        float4* __restrict__ o = out + base;
        for (long long i = tid; i < n4; i += stride) {
            float4 v = p[i];
            v.x *= scale; v.y *= scale; v.z *= scale; v.w *= scale;
            o[i] = v;
        }
        base += n4;
    }
}

extern "C" void kernel_launch(void* const* d_in, const int* in_sizes, int n_in,
                              void* d_out, int out_size, void* d_ws, size_t ws_size,
                              hipStream_t stream) {
    Args5 args;
    for (int t = 0; t < NT; ++t) {
        args.p[t] = (const float4*)d_in[t];
        args.n4[t] = (long long)in_sizes[t] / 4;
    }
    double* acc = (double*)d_ws;

    // ws is poisoned to 0xAA before every timed call — zero the accumulator.
    hipMemsetAsync(acc, 0, sizeof(double), stream);

    reduce_sq_kernel<<<GRID, BLOCK, 0, stream>>>(args, acc);
    scale_kernel<<<GRID, BLOCK, 0, stream>>>(args, (float4*)d_out, acc);
}